// Round 6
// baseline (258.448 us; speedup 1.0000x reference)
//
#include <hip/hip_runtime.h>
#include <math.h>

// fp32 in / fp32 out. Five kernel symbols (conv / p0 / attn / ffn1 / ffn2).
// B=2,T=2048,D=1024,NH=16,NKV=4,HD=64,WIN=128,M=4096.
//
// ws layout (float slots):
//   Y      @ 0           : QKV f32 [4096][1536]        (dead after attn)
//   x_bf   @ 6,291,456   : x bf16 [4096][1024]         (dead after P0)
//   wqkv_bf@ 8,388,608   : [1536][1024] bf16           (dead after P0)
//   o_bf   @ 8,388,608   : attn out bf16 [4096][1024]  (over wqkv; dead after ffn1)
//   w1_bf  @ 10,485,760  : [4096][1024] bf16           (dead after ffn1)
//   h_bf   @ 0           : FFN1 out bf16 [4096][4096]  (over dead Y+x_bf)
//   w2_bf  @ 8,388,608   : [1024][4096] bf16           (over dead o_bf, conv6)
//
// Sequence: conv5 | P0 QKV+RoPE->Y | attn->o_bf | ffn1 (silu->h_bf) |
//           conv6 (W2->bf16, zero out) | ffn2 (128^2 split-K x2, atomicAdd).
//
// r5 lessons (measured): ffn2 64x128 tile = half the FLOP/LDS-byte of 128^2
//   -> 286 TF ceiling (MfmaUtil 22.6). 128^2 is the balanced tile (64KB LDS
//   reads ~ 2.1 MFLOP ~ 128 B/cyc vs MFMA peak). attn at grid 256 = 1 wave/
//   SIMD -> zero TLP; 32-row q-tiles double occupancy at equal MFMA/q-row.
// T1 XCD swizzle on all grids (bijective, n%8==0). LDS XOR swizzle on GEMMs
//   (r2->r3: conflicts 6.29M -> 0): phys chunk = logical ^ (row&7), inverse
//   applied at per-lane GLOBAL source, same XOR on reads.
// MFMA layouts (HW-verified m89/m91): A[m=lane&15][k=(lane>>4)*8+j],
//   B[n=lane&15][k=same], D: col=lane&15, row=(lane>>4)*4+reg.

typedef __bf16 bf16x8 __attribute__((ext_vector_type(8)));
typedef __bf16 bf16x4 __attribute__((ext_vector_type(4)));
typedef float  f32x4  __attribute__((ext_vector_type(4)));

extern __shared__ __align__(16) char smem[];

#define GLOAD_LDS16(g, l) __builtin_amdgcn_global_load_lds(               \
    (const __attribute__((address_space(1))) void*)(g),                   \
    (__attribute__((address_space(3))) void*)(l), 16, 0, 0)

__device__ __forceinline__ unsigned pk2(float a, float b) {
    union { __bf16 h[2]; unsigned u; } t;
    t.h[0] = (__bf16)a; t.h[1] = (__bf16)b;
    return t.u;
}

__device__ __forceinline__ int xcd_swz(int bid, int n) {
    return (bid & 7) * (n >> 3) + (bid >> 3);
}

// ---------------------------------------------------------------- conv ----
__global__ __launch_bounds__(256) void MultiAttention_60722247631706_conv(
    const float* x, const float* Wq, const float* Wk, const float* Wv,
    const float* W1, const float* W2, float* out, float* ws, int phase)
{
    __bf16* xbf    = (__bf16*)(ws + 6291456);
    __bf16* wqkvbf = (__bf16*)(ws + 8388608);
    __bf16* w1bf   = (__bf16*)(ws + 10485760);
    __bf16* w2bf   = (__bf16*)(ws + 8388608);
    const int tid = threadIdx.x;

    if (phase == 5) {
        const long long total4 = 9961472 / 4;
        for (long long i4 = (long long)blockIdx.x * 256 + tid; i4 < total4;
             i4 += (long long)gridDim.x * 256) {
            const long long i = i4 * 4;
            const float* src; __bf16* dst;
            if (i < 4194304)      { src = x  + i;             dst = xbf    + i; }
            else if (i < 5242880) { src = Wq + (i - 4194304); dst = wqkvbf + (i - 4194304); }
            else if (i < 5505024) { src = Wk + (i - 5242880); dst = wqkvbf + (i - 4194304); }
            else if (i < 5767168) { src = Wv + (i - 5505024); dst = wqkvbf + (i - 4194304); }
            else                  { src = W1 + (i - 5767168); dst = w1bf   + (i - 5767168); }
            const f32x4 v = *(const f32x4*)src;
            bf16x4 o;
            o[0] = (__bf16)v[0]; o[1] = (__bf16)v[1];
            o[2] = (__bf16)v[2]; o[3] = (__bf16)v[3];
            *(bf16x4*)dst = o;
        }
    } else {
        // convert W2 -> w2_bf, and zero `out` for ffn2's atomic split-K
        const long long total4 = 4194304 / 4;
        for (long long i4 = (long long)blockIdx.x * 256 + tid; i4 < total4;
             i4 += (long long)gridDim.x * 256) {
            const long long i = i4 * 4;
            const f32x4 v = *(const f32x4*)(W2 + i);
            bf16x4 o;
            o[0] = (__bf16)v[0]; o[1] = (__bf16)v[1];
            o[2] = (__bf16)v[2]; o[3] = (__bf16)v[3];
            *(bf16x4*)(w2bf + i) = o;
        }
        const f32x4 z = {0.f, 0.f, 0.f, 0.f};
        for (long long i4 = (long long)blockIdx.x * 256 + tid; i4 < total4;
             i4 += (long long)gridDim.x * 256) {
            *(f32x4*)(out + i4 * 4) = z;
        }
    }
}

// ---------------------------------------------------------------- attn ----
// Grid 512 = (b=2, kvh=4, qt=64 of 32 rows). 4 waves = 4 GQA heads.
// 2 blocks/CU (LDS 53KB) -> 2 waves/SIMD (r5: was 1 wave/SIMD at grid 256).
// LDS window still 192 K-rows (3x64 kb-blocks); rows beyond the 160-row
// valid span are staged as zeros and masked (dlt<=128 keeps kl<160).
__global__ __launch_bounds__(256) void MultiAttention_60722247631706_attn(
    float* ws)
{
    const float* Y = ws;
    __bf16* obf = (__bf16*)(ws + 8388608);

    __bf16* Ks = (__bf16*)smem;          // [192][72]
    __bf16* Vt = Ks + 192 * 72;          // [64][200]  (V transposed: Vt[d][j])

    const int sb  = xcd_swz(blockIdx.x, 512);
    const int qt  = sb & 63;
    const int kvh = (sb >> 6) & 3;
    const int b   = sb >> 8;
    const int q0  = qt * 32;
    const int wb  = q0 - 128;            // LDS row r <-> key j = wb + r

    const int tid  = threadIdx.x;
    const int w    = tid >> 6;
    const int lane = tid & 63;
    const int l16  = lane & 15;
    const int quad = lane >> 4;
    const int h    = kvh * 4 + w;

    const float* Yb = Y + (size_t)b * 2048 * 1536;

    for (int i = tid; i < 192 * 8; i += 256) {
        const int r  = i >> 3;
        const int c8 = (i & 7) * 8;
        const int j  = wb + r;
        bf16x8 kv;
        if (j >= 0 && j < 2048) {
            const float* kp = Yb + (size_t)j * 1536 + 1024 + kvh * 64 + c8;
            const f32x4 a = *(const f32x4*)kp;
            const f32x4 c = *(const f32x4*)(kp + 4);
            kv[0] = (__bf16)a[0]; kv[1] = (__bf16)a[1];
            kv[2] = (__bf16)a[2]; kv[3] = (__bf16)a[3];
            kv[4] = (__bf16)c[0]; kv[5] = (__bf16)c[1];
            kv[6] = (__bf16)c[2]; kv[7] = (__bf16)c[3];
        } else {
            const __bf16 z = (__bf16)0.f;
            kv[0]=z; kv[1]=z; kv[2]=z; kv[3]=z; kv[4]=z; kv[5]=z; kv[6]=z; kv[7]=z;
        }
        *(bf16x8*)(Ks + r * 72 + c8) = kv;
    }
    for (int i = tid; i < 192 * 16; i += 256) {
        const int r  = i >> 4;
        const int c4 = (i & 15) * 4;
        const int j  = wb + r;
        f32x4 vv = {0.f, 0.f, 0.f, 0.f};
        if (j >= 0 && j < 2048)
            vv = *(const f32x4*)(Yb + (size_t)j * 1536 + 1280 + kvh * 64 + c4);
        Vt[(c4 + 0) * 200 + r] = (__bf16)vv[0];
        Vt[(c4 + 1) * 200 + r] = (__bf16)vv[1];
        Vt[(c4 + 2) * 200 + r] = (__bf16)vv[2];
        Vt[(c4 + 3) * 200 + r] = (__bf16)vv[3];
    }

    // Q B-fragments (scale folded): qf[qn][kk], q=l16, d=kk*32+quad*8+j
    bf16x8 qf[2][2];
#pragma unroll
    for (int qn = 0; qn < 2; ++qn)
#pragma unroll
        for (int kk = 0; kk < 2; ++kk) {
            const float* qp = Yb + (size_t)(q0 + qn * 16 + l16) * 1536
                              + h * 64 + kk * 32 + quad * 8;
            const f32x4 a = *(const f32x4*)qp;
            const f32x4 c = *(const f32x4*)(qp + 4);
            bf16x8 t;
            t[0] = (__bf16)(a[0] * 0.125f); t[1] = (__bf16)(a[1] * 0.125f);
            t[2] = (__bf16)(a[2] * 0.125f); t[3] = (__bf16)(a[3] * 0.125f);
            t[4] = (__bf16)(c[0] * 0.125f); t[5] = (__bf16)(c[1] * 0.125f);
            t[6] = (__bf16)(c[2] * 0.125f); t[7] = (__bf16)(c[3] * 0.125f);
            qf[qn][kk] = t;
        }

    __syncthreads();

    f32x4 oacc[2][4];
#pragma unroll
    for (int qm = 0; qm < 2; ++qm)
#pragma unroll
        for (int dn = 0; dn < 4; ++dn) {
            f32x4 z = {0.f, 0.f, 0.f, 0.f};
            oacc[qm][dn] = z;
        }
    float m_run[2] = {-1e30f, -1e30f};
    float l_run[2] = {0.f, 0.f};

    const int kclip = -wb;               // j>=0  <=>  k_local >= kclip

    for (int kb = 0; kb < 3; ++kb) {
        f32x4 s[4][2];
#pragma unroll
        for (int km = 0; km < 4; ++km)
#pragma unroll
            for (int qn = 0; qn < 2; ++qn) {
                f32x4 z = {0.f, 0.f, 0.f, 0.f};
                s[km][qn] = z;
            }
#pragma unroll
        for (int kk = 0; kk < 2; ++kk) {
            bf16x8 kf[4];
#pragma unroll
            for (int km = 0; km < 4; ++km)
                kf[km] = *(const bf16x8*)(Ks + (kb * 64 + km * 16 + l16) * 72
                                          + kk * 32 + quad * 8);
#pragma unroll
            for (int km = 0; km < 4; ++km)
#pragma unroll
                for (int qn = 0; qn < 2; ++qn)
                    s[km][qn] = __builtin_amdgcn_mfma_f32_16x16x32_bf16(
                        kf[km], qf[qn][kk], s[km][qn], 0, 0, 0);
        }

        unsigned cu[2][4][2];
        float corr[2];
#pragma unroll
        for (int qn = 0; qn < 2; ++qn) {
            float mx = -1e30f;
#pragma unroll
            for (int km = 0; km < 4; ++km)
#pragma unroll
                for (int r = 0; r < 4; ++r) {
                    const int kl  = kb * 64 + km * 16 + quad * 4 + r;
                    const int dlt = kl - (qn * 16 + l16);
                    const bool ok = (dlt >= 1) && (dlt <= 128) && (kl >= kclip);
                    const float sv = ok ? s[km][qn][r] : -1e30f;
                    s[km][qn][r] = sv;
                    mx = fmaxf(mx, sv);
                }
            mx = fmaxf(mx, __shfl_xor(mx, 16));
            mx = fmaxf(mx, __shfl_xor(mx, 32));
            const float mnew = fmaxf(fmaxf(m_run[qn], mx), -1e20f);
            corr[qn] = expf(m_run[qn] - mnew);
            m_run[qn] = mnew;
            float rowsum = 0.f;
#pragma unroll
            for (int km = 0; km < 4; ++km) {
#pragma unroll
                for (int r = 0; r < 4; ++r) {
                    const float p = expf(s[km][qn][r] - mnew);
                    s[km][qn][r] = p;
                    rowsum += p;
                }
                cu[qn][km][0] = pk2(s[km][qn][0], s[km][qn][1]);
                cu[qn][km][1] = pk2(s[km][qn][2], s[km][qn][3]);
            }
            rowsum += __shfl_xor(rowsum, 16);
            rowsum += __shfl_xor(rowsum, 32);
            l_run[qn] = l_run[qn] * corr[qn] + rowsum;
        }

#pragma unroll
        for (int qm = 0; qm < 2; ++qm)
#pragma unroll
            for (int r = 0; r < 4; ++r) {
                const float f = __shfl(corr[qm], (lane & 48) | (quad * 4 + r));
                oacc[qm][0][r] *= f; oacc[qm][1][r] *= f;
                oacc[qm][2][r] *= f; oacc[qm][3][r] *= f;
            }

#pragma unroll
        for (int kk = 0; kk < 2; ++kk) {
            bf16x8 vf[4];
#pragma unroll
            for (int dn = 0; dn < 4; ++dn)
                vf[dn] = *(const bf16x8*)(Vt + (dn * 16 + l16) * 200
                                          + kb * 64 + kk * 32 + quad * 8);
            const int srcA = ((quad & 1) * 32) + l16;
            const int hi   = quad >> 1;
#pragma unroll
            for (int qm = 0; qm < 2; ++qm) {
                const unsigned a0 = (unsigned)__shfl((int)cu[qm][2*kk  ][0], srcA);
                const unsigned a1 = (unsigned)__shfl((int)cu[qm][2*kk  ][1], srcA);
                const unsigned b0 = (unsigned)__shfl((int)cu[qm][2*kk+1][0], srcA);
                const unsigned b1 = (unsigned)__shfl((int)cu[qm][2*kk+1][1], srcA);
                const unsigned c0 = (unsigned)__shfl((int)cu[qm][2*kk  ][0], srcA + 16);
                const unsigned c1 = (unsigned)__shfl((int)cu[qm][2*kk  ][1], srcA + 16);
                const unsigned d0 = (unsigned)__shfl((int)cu[qm][2*kk+1][0], srcA + 16);
                const unsigned d1 = (unsigned)__shfl((int)cu[qm][2*kk+1][1], srcA + 16);
                union { unsigned u[4]; bf16x8 v; } af;
                af.u[0] = hi ? b0 : a0;
                af.u[1] = hi ? b1 : a1;
                af.u[2] = hi ? d0 : c0;
                af.u[3] = hi ? d1 : c1;
#pragma unroll
                for (int dn = 0; dn < 4; ++dn)
                    oacc[qm][dn] = __builtin_amdgcn_mfma_f32_16x16x32_bf16(
                        af.v, vf[dn], oacc[qm][dn], 0, 0, 0);
            }
        }
    }

#pragma unroll
    for (int qm = 0; qm < 2; ++qm) {
        const float rl = 1.f / l_run[qm];
#pragma unroll
        for (int r = 0; r < 4; ++r) {
            const float f = __shfl(rl, (lane & 48) | (quad * 4 + r));
            const int q = q0 + qm * 16 + quad * 4 + r;
            __bf16* op = obf + ((size_t)(b * 2048 + q)) * 1024 + h * 64 + l16;
#pragma unroll
            for (int dn = 0; dn < 4; ++dn)
                op[dn * 16] = (__bf16)(oacc[qm][dn][r] * f);
        }
    }
}

// ------------------------------------------------------------------ p0 ----
// Y = x@Wqkv^T (+RoPE). 64x128 tile (M x N), grid 64*12=768 (3 blocks/CU).
__global__ __launch_bounds__(256, 4) void MultiAttention_60722247631706_p0(
    float* ws)
{
    float*  Y      = ws;
    __bf16* xbf    = (__bf16*)(ws + 6291456);
    __bf16* wqkvbf = (__bf16*)(ws + 8388608);

    const int tid = threadIdx.x;

    __bf16* As = (__bf16*)smem;       // [64][64]
    __bf16* Bs = As + 64 * 64;        // [128][64]

    const int bid  = xcd_swz(blockIdx.x, 768);
    const int tm   = bid / 12;        // 0..63
    const int tn   = bid % 12;        // 0..11
    const int w    = tid >> 6;
    const int lane = tid & 63;
    const int wr   = w >> 1;
    const int wc   = w & 1;
    const int l16  = lane & 15;
    const int quad = lane >> 4;
    const int srow = lane >> 3;
    const int sch  = ((lane & 7) ^ srow) * 8;

    const __bf16* ga0 = xbf    + (size_t)(tm * 64  + w * 16 + srow) * 1024 + sch;
    const __bf16* gb0 = wqkvbf + (size_t)(tn * 128 + w * 32 + srow) * 1024 + sch;

    f32x4 zero = {0.f, 0.f, 0.f, 0.f};
    f32x4 acc[2][4];
#pragma unroll
    for (int mi = 0; mi < 2; ++mi)
#pragma unroll
        for (int ni = 0; ni < 4; ++ni) acc[mi][ni] = zero;

    for (int k0 = 0; k0 < 1024; k0 += 64) {
#pragma unroll
        for (int i = 0; i < 2; ++i)
            GLOAD_LDS16(ga0 + (size_t)i * 8 * 1024 + k0, As + (w * 16 + i * 8) * 64);
#pragma unroll
        for (int i = 0; i < 4; ++i)
            GLOAD_LDS16(gb0 + (size_t)i * 8 * 1024 + k0, Bs + (w * 32 + i * 8) * 64);
        __syncthreads();
#pragma unroll
        for (int kk = 0; kk < 2; ++kk) {
            const int cs = ((kk * 4 + quad) ^ (l16 & 7)) * 8;
            bf16x8 af[2], bfr[4];
#pragma unroll
            for (int mi = 0; mi < 2; ++mi)
                af[mi] = *(const bf16x8*)(As + (size_t)(wr * 32 + mi * 16 + l16) * 64 + cs);
#pragma unroll
            for (int ni = 0; ni < 4; ++ni)
                bfr[ni] = *(const bf16x8*)(Bs + (size_t)(wc * 64 + ni * 16 + l16) * 64 + cs);
#pragma unroll
            for (int mi = 0; mi < 2; ++mi)
#pragma unroll
                for (int ni = 0; ni < 4; ++ni)
                    acc[mi][ni] = __builtin_amdgcn_mfma_f32_16x16x32_bf16(
                        af[mi], bfr[ni], acc[mi][ni], 0, 0, 0);
        }
        __syncthreads();
    }

    const int mbase = tm * 64 + wr * 32;
    const int nbase = tn * 128 + wc * 64;   // multiple of 64 -> head-aligned

    const bool rot = nbase < 1280;          // Q (n<1024) and K (1024..1279)
    const float inv1 = powf(10000.f, -(float)l16 / 32.f);
    const float inv2 = powf(10000.f, -(float)(16 + l16) / 32.f);
#pragma unroll
    for (int mi = 0; mi < 2; ++mi) {
#pragma unroll
        for (int r = 0; r < 4; ++r) {
            const int m = mbase + mi * 16 + quad * 4 + r;
            const int t = m & 2047;
            float v0 = acc[mi][0][r], v1 = acc[mi][1][r];
            float v2 = acc[mi][2][r], v3 = acc[mi][3][r];
            if (rot) {
                const float a1 = (float)t * inv1, a2 = (float)t * inv2;
                const float c1 = cosf(a1), s1 = sinf(a1);
                const float c2 = cosf(a2), s2 = sinf(a2);
                const float n0 = v0 * c1 - v2 * s1;
                const float n2 = v0 * s1 + v2 * c1;
                const float n1 = v1 * c2 - v3 * s2;
                const float n3 = v1 * s2 + v3 * c2;
                v0 = n0; v1 = n1; v2 = n2; v3 = n3;
            }
            float* yp = Y + (size_t)m * 1536 + nbase + l16;
            yp[0] = v0; yp[16] = v1; yp[32] = v2; yp[48] = v3;
        }
    }
}

// ---------------------------------------------------------------- ffn1 ----
// H = silu(o@W1^T): 128x128 tile, 4 waves, grid 32*32=1024 (4 blocks/CU).
__global__ __launch_bounds__(256, 4) void MultiAttention_60722247631706_ffn1(
    float* ws)
{
    __bf16* obf  = (__bf16*)(ws + 8388608);
    __bf16* w1bf = (__bf16*)(ws + 10485760);
    __bf16* hbf  = (__bf16*)ws;

    const int tid = threadIdx.x;

    __bf16* As = (__bf16*)smem;       // [128][64]
    __bf16* Bs = As + 128 * 64;       // [128][64]

    const int bid  = xcd_swz(blockIdx.x, 1024);
    const int tm   = bid >> 5;        // 0..31
    const int tn   = bid & 31;        // 0..31
    const int w    = tid >> 6;
    const int lane = tid & 63;
    const int wr   = w >> 1;
    const int wc   = w & 1;
    const int l16  = lane & 15;
    const int quad = lane >> 4;
    const int srow = lane >> 3;
    const int sch  = ((lane & 7) ^ srow) * 8;

    const __bf16* ga0 = obf  + (size_t)(tm * 128 + w * 32 + srow) * 1024 + sch;
    const __bf16* gb0 = w1bf + (size_t)(tn * 128 + w * 32 + srow) * 1024 + sch;

    f32x4 zero = {0.f, 0.f, 0.f, 0.f};
    f32x4 acc[4][4];
#pragma unroll
    for (int mi = 0; mi < 4; ++mi)
#pragma unroll
        for (int ni = 0; ni < 4; ++ni) acc[mi][ni] = zero;

    for (int k0 = 0; k0 < 1024; k0 += 64) {
#pragma unroll
        for (int i = 0; i < 4; ++i) {
            GLOAD_LDS16(ga0 + (size_t)i * 8 * 1024 + k0, As + (w * 32 + i * 8) * 64);
            GLOAD_LDS16(gb0 + (size_t)i * 8 * 1024 + k0, Bs + (w * 32 + i * 8) * 64);
        }
        __syncthreads();
#pragma unroll
        for (int kk = 0; kk < 2; ++kk) {
            const int cs = ((kk * 4 + quad) ^ (l16 & 7)) * 8;
            bf16x8 af[4], bfr[4];
#pragma unroll
            for (int mi = 0; mi < 4; ++mi)
                af[mi] = *(const bf16x8*)(As + (size_t)(wr * 64 + mi * 16 + l16) * 64 + cs);
#pragma unroll
            for (int ni = 0; ni < 4; ++ni)
                bfr[ni] = *(const bf16x8*)(Bs + (size_t)(wc * 64 + ni * 16 + l16) * 64 + cs);
#pragma unroll
            for (int mi = 0; mi < 4; ++mi)
#pragma unroll
                for (int ni = 0; ni < 4; ++ni)
                    acc[mi][ni] = __builtin_amdgcn_mfma_f32_16x16x32_bf16(
                        af[mi], bfr[ni], acc[mi][ni], 0, 0, 0);
        }
        __syncthreads();
    }

#pragma unroll
    for (int mi = 0; mi < 4; ++mi) {
#pragma unroll
        for (int r = 0; r < 4; ++r) {
            const int m = tm * 128 + wr * 64 + mi * 16 + quad * 4 + r;
            __bf16* hp = hbf + (size_t)m * 4096 + tn * 128 + wc * 64 + l16;
#pragma unroll
            for (int ni = 0; ni < 4; ++ni) {
                const float v = acc[mi][ni][r];
                hp[ni * 16] = (__bf16)(v / (1.f + expf(-v)));   // silu
            }
        }
    }
}

// ---------------------------------------------------------------- ffn2 ----
// out += H_ks @ W2_ks^T: 128x128 tile, split-K x2, grid 512 (2/CU), atomicAdd.
// r5 lesson: 64x128 halves FLOP/LDS-byte -> 286 TF; 128^2 is the balanced tile.
__global__ __launch_bounds__(256, 4) void MultiAttention_60722247631706_ffn2(
    float* out, float* ws)
{
    __bf16* hbf  = (__bf16*)ws;
    __bf16* w2bf = (__bf16*)(ws + 8388608);

    int bid = xcd_swz(blockIdx.x, 512);
    const int ks = bid >> 8;  bid &= 255;
    const int tm = bid >> 3;          // 0..31
    const int tn = bid & 7;           // 0..7
    const int kbase = ks * 2048;

    const int tid  = threadIdx.x;
    const int w    = tid >> 6;
    const int lane = tid & 63;
    const int wr   = w >> 1;
    const int wc   = w & 1;
    const int l16  = lane & 15;
    const int quad = lane >> 4;
    const int srow = lane >> 3;
    const int sch  = ((lane & 7) ^ srow) * 8;

    __bf16* As = (__bf16*)smem;       // [128][64]
    __bf16* Bs = As + 128 * 64;       // [128][64]

    const __bf16* ga0 = hbf  + (size_t)(tm * 128 + w * 32 + srow) * 4096 + kbase + sch;
    const __bf16* gb0 = w2bf + (size_t)(tn * 128 + w * 32 + srow) * 4096 + kbase + sch;

    f32x4 zero = {0.f, 0.f, 0.f, 0.f};
    f32x4 acc[4][4];
#pragma unroll
    for (int mi = 0; mi < 4; ++mi)
#pragma unroll
        for (int ni = 0; ni < 4; ++ni) acc[mi][ni] = zero;

    for (int k0 = 0; k0 < 2048; k0 += 64) {
#pragma unroll
        for (int i = 0; i < 4; ++i) {
            GLOAD_LDS16(ga0 + (size_t)i * 8 * 4096 + k0, As + (w * 32 + i * 8) * 64);
            GLOAD_LDS16(gb0 + (size_t)i * 8 * 4096 + k0, Bs + (w * 32 + i * 8) * 64);
        }
        __syncthreads();
#pragma unroll
        for (int kk = 0; kk < 2; ++kk) {
            const int cs = ((kk * 4 + quad) ^ (l16 & 7)) * 8;
            bf16x8 af[4], bfr[4];
#pragma unroll
            for (int mi = 0; mi < 4; ++mi)
                af[mi] = *(const bf16x8*)(As + (size_t)(wr * 64 + mi * 16 + l16) * 64 + cs);
#pragma unroll
            for (int ni = 0; ni < 4; ++ni)
                bfr[ni] = *(const bf16x8*)(Bs + (size_t)(wc * 64 + ni * 16 + l16) * 64 + cs);
#pragma unroll
            for (int mi = 0; mi < 4; ++mi)
#pragma unroll
                for (int ni = 0; ni < 4; ++ni)
                    acc[mi][ni] = __builtin_amdgcn_mfma_f32_16x16x32_bf16(
                        af[mi], bfr[ni], acc[mi][ni], 0, 0, 0);
        }
        __syncthreads();
    }

#pragma unroll
    for (int mi = 0; mi < 4; ++mi) {
#pragma unroll
        for (int r = 0; r < 4; ++r) {
            const int m = tm * 128 + wr * 64 + mi * 16 + quad * 4 + r;
            float* op = out + (size_t)m * 1024 + tn * 128 + wc * 64 + l16;
#pragma unroll
            for (int ni = 0; ni < 4; ++ni)
                atomicAdd(op + ni * 16, acc[mi][ni][r]);
        }
    }
}

extern "C" void kernel_launch(void* const* d_in, const int* in_sizes, int n_in,
                              void* d_out, int out_size, void* d_ws, size_t ws_size,
                              hipStream_t stream)
{
    const float* x  = (const float*)d_in[0];
    const float* Wq = (const float*)d_in[1];
    const float* Wk = (const float*)d_in[2];
    const float* Wv = (const float*)d_in[3];
    const float* W1 = (const float*)d_in[4];
    const float* W2 = (const float*)d_in[5];
    float* out = (float*)d_out;
    float* ws  = (float*)d_ws;

    const int P0_LDS   = (64 + 128) * 64 * 2;              // 24576 B
    const int ATTN_LDS = (192 * 72 + 64 * 200) * 2;        // 53248 B
    const int FFN1_LDS = 2 * 128 * 64 * 2;                 // 32768 B
    const int FFN2_LDS = 2 * 128 * 64 * 2;                 // 32768 B

    // conv: x, Wq|Wk|Wv, W1 -> bf16
    MultiAttention_60722247631706_conv<<<2048, 256, 0, stream>>>(
        x, Wq, Wk, Wv, W1, W2, out, ws, 5);
    // P0: QKV GEMM + fused RoPE -> Y f32 [4096][1536]
    MultiAttention_60722247631706_p0<<<768, 256, P0_LDS, stream>>>(ws);
    // attention -> o_bf (grid 512: 32-row q-tiles, 2 blocks/CU)
    MultiAttention_60722247631706_attn<<<512, 256, ATTN_LDS, stream>>>(ws);
    // FFN1 -> h_bf
    MultiAttention_60722247631706_ffn1<<<1024, 256, FFN1_LDS, stream>>>(ws);
    // conv: W2 -> bf16 (over dead o_bf) + zero `out`
    MultiAttention_60722247631706_conv<<<1024, 256, 0, stream>>>(
        x, Wq, Wk, Wv, W1, W2, out, ws, 6);
    // FFN2: 128^2 split-K x2, atomicAdd into out
    MultiAttention_60722247631706_ffn2<<<512, 256, FFN2_LDS, stream>>>(out, ws);
}

// Round 7
// 247.012 us; speedup vs baseline: 1.0463x; 1.0463x over previous
//
#include <hip/hip_runtime.h>
#include <math.h>

// fp32 in / fp32 out. Five kernel symbols (conv / p0 / attn / ffn1 / ffn2).
// B=2,T=2048,D=1024,NH=16,NKV=4,HD=64,WIN=128,M=4096.
//
// ws layout (float slots):
//   q_bf   @ 0           : Q bf16 [4096][1024], RoPE'd, pre-scaled 0.125
//   k_bf   @ 2,097,152   : K bf16 [4096][256], RoPE'd
//   vt_bf  @ 2,621,440   : V^T bf16 [2][4][64][2048]
//   x_bf   @ 6,291,456   : x bf16 [4096][1024]         (dead after p0)
//   wqkv_bf@ 8,388,608   : [1536][1024] bf16           (dead after p0)
//   o_bf   @ 8,388,608   : attn out bf16 [4096][1024]  (over wqkv; dead after ffn1)
//   w1_bf  @ 10,485,760  : [4096][1024] bf16           (dead after ffn1)
//   h_bf   @ 0           : FFN1 out bf16 [4096][4096]  (over dead q/k/vt)
//   w2_bf  @ 8,388,608   : [1024][4096] bf16           (over dead o_bf, conv6)
//
// Sequence: conv5 | p0 QKV+RoPE->q/k/vt bf16 | attn->o_bf | ffn1->h_bf |
//           conv6 (W2->bf16, zero out) | ffn2 (64x128 split-K x2, atomicAdd).
//
// r6 lessons (measured): attn 32-row tiles doubled staging/block -> +7us;
//   ffn2 128^2/grid-512 traded occupancy for tile FLOP-density -> -1.6us.
//   Fix: attention v2 has NO LDS staging at all — Q/K/V^T are small bf16
//   L1/L2-resident arrays written by p0 in MFMA-fragment-friendly layouts;
//   16-row q-tiles, grid 1024, 4 waves/SIMD, no barriers (Common-mistake #7).
// T1 XCD swizzle on all grids. LDS XOR swizzle on GEMM tiles (r2->r3:
//   conflicts 6.29M -> 0). MFMA layouts (HW-verified m89/m91):
//   A[m=lane&15][k=(lane>>4)*8+j], B[n=lane&15][k=same],
//   D: col=lane&15, row=(lane>>4)*4+reg.

typedef __bf16 bf16x8 __attribute__((ext_vector_type(8)));
typedef __bf16 bf16x4 __attribute__((ext_vector_type(4)));
typedef float  f32x4  __attribute__((ext_vector_type(4)));

extern __shared__ __align__(16) char smem[];

#define GLOAD_LDS16(g, l) __builtin_amdgcn_global_load_lds(               \
    (const __attribute__((address_space(1))) void*)(g),                   \
    (__attribute__((address_space(3))) void*)(l), 16, 0, 0)

__device__ __forceinline__ unsigned pk2(float a, float b) {
    union { __bf16 h[2]; unsigned u; } t;
    t.h[0] = (__bf16)a; t.h[1] = (__bf16)b;
    return t.u;
}

__device__ __forceinline__ int xcd_swz(int bid, int n) {
    return (bid & 7) * (n >> 3) + (bid >> 3);
}

// ---------------------------------------------------------------- conv ----
__global__ __launch_bounds__(256) void MultiAttention_60722247631706_conv(
    const float* x, const float* Wq, const float* Wk, const float* Wv,
    const float* W1, const float* W2, float* out, float* ws, int phase)
{
    __bf16* xbf    = (__bf16*)(ws + 6291456);
    __bf16* wqkvbf = (__bf16*)(ws + 8388608);
    __bf16* w1bf   = (__bf16*)(ws + 10485760);
    __bf16* w2bf   = (__bf16*)(ws + 8388608);
    const int tid = threadIdx.x;

    if (phase == 5) {
        const long long total4 = 9961472 / 4;
        for (long long i4 = (long long)blockIdx.x * 256 + tid; i4 < total4;
             i4 += (long long)gridDim.x * 256) {
            const long long i = i4 * 4;
            const float* src; __bf16* dst;
            if (i < 4194304)      { src = x  + i;             dst = xbf    + i; }
            else if (i < 5242880) { src = Wq + (i - 4194304); dst = wqkvbf + (i - 4194304); }
            else if (i < 5505024) { src = Wk + (i - 5242880); dst = wqkvbf + (i - 4194304); }
            else if (i < 5767168) { src = Wv + (i - 5505024); dst = wqkvbf + (i - 4194304); }
            else                  { src = W1 + (i - 5767168); dst = w1bf   + (i - 5767168); }
            const f32x4 v = *(const f32x4*)src;
            bf16x4 o;
            o[0] = (__bf16)v[0]; o[1] = (__bf16)v[1];
            o[2] = (__bf16)v[2]; o[3] = (__bf16)v[3];
            *(bf16x4*)dst = o;
        }
    } else {
        // convert W2 -> w2_bf, and zero `out` for ffn2's atomic split-K
        const long long total4 = 4194304 / 4;
        for (long long i4 = (long long)blockIdx.x * 256 + tid; i4 < total4;
             i4 += (long long)gridDim.x * 256) {
            const long long i = i4 * 4;
            const f32x4 v = *(const f32x4*)(W2 + i);
            bf16x4 o;
            o[0] = (__bf16)v[0]; o[1] = (__bf16)v[1];
            o[2] = (__bf16)v[2]; o[3] = (__bf16)v[3];
            *(bf16x4*)(w2bf + i) = o;
        }
        const f32x4 z = {0.f, 0.f, 0.f, 0.f};
        for (long long i4 = (long long)blockIdx.x * 256 + tid; i4 < total4;
             i4 += (long long)gridDim.x * 256) {
            *(f32x4*)(out + i4 * 4) = z;
        }
    }
}

// ---------------------------------------------------------------- attn ----
// v2: no LDS, no barriers. Grid 1024 = (b=2, kvh=4, qt=128 of 16 rows),
// 4 waves = 4 GQA heads (same kvh -> K/V frag loads L1-hit across waves).
// All MFMA fragments loaded directly from bf16 global (16B contiguous).
// OOB window rows: address clamped to 0; mask gives p=0 exactly for them.
__global__ __launch_bounds__(256, 4) void MultiAttention_60722247631706_attn(
    float* ws)
{
    const __bf16* qbf  = (const __bf16*)ws;
    const __bf16* kbf  = (const __bf16*)(ws + 2097152);
    const __bf16* vtbf = (const __bf16*)(ws + 2621440);
    __bf16*       obf  = (__bf16*)(ws + 8388608);

    const int sb  = xcd_swz(blockIdx.x, 1024);
    const int qt  = sb & 127;
    const int kvh = (sb >> 7) & 3;
    const int b   = sb >> 9;
    const int q0  = qt * 16;
    const int wb  = q0 - 128;            // k-window local kl <-> key j = wb + kl

    const int tid  = threadIdx.x;
    const int w    = tid >> 6;
    const int lane = tid & 63;
    const int l16  = lane & 15;
    const int quad = lane >> 4;
    const int h    = kvh * 4 + w;

    const __bf16* Kb = kbf + (size_t)b * 2048 * 256 + kvh * 64;
    const __bf16* Vb = vtbf + (size_t)(b * 4 + kvh) * 64 * 2048;

    // Q B-fragments (pre-scaled, pre-roped by p0): q=l16, d=kk*32+quad*8+j
    bf16x8 qf[2];
#pragma unroll
    for (int kk = 0; kk < 2; ++kk)
        qf[kk] = *(const bf16x8*)(qbf + (size_t)(b * 2048 + q0 + l16) * 1024
                                  + h * 64 + kk * 32 + quad * 8);

    f32x4 oacc[4];
#pragma unroll
    for (int dn = 0; dn < 4; ++dn) {
        f32x4 z = {0.f, 0.f, 0.f, 0.f};
        oacc[dn] = z;
    }
    float m_run = -1e30f, l_run = 0.f;
    const int kclip = -wb;               // j>=0  <=>  kl >= kclip

    for (int kb = 0; kb < 3; ++kb) {
        // ---- S^T = K @ Q^T (lane: q=l16, k=km*16+quad*4+r)
        f32x4 s[4];
#pragma unroll
        for (int km = 0; km < 4; ++km) {
            f32x4 z = {0.f, 0.f, 0.f, 0.f};
            s[km] = z;
        }
#pragma unroll
        for (int kk = 0; kk < 2; ++kk) {
            bf16x8 kf[4];
#pragma unroll
            for (int km = 0; km < 4; ++km) {
                int row = wb + kb * 64 + km * 16 + l16;
                row = (row >= 0 && row < 2048) ? row : 0;   // masked anyway
                kf[km] = *(const bf16x8*)(Kb + (size_t)row * 256
                                          + kk * 32 + quad * 8);
            }
#pragma unroll
            for (int km = 0; km < 4; ++km)
                s[km] = __builtin_amdgcn_mfma_f32_16x16x32_bf16(
                    kf[km], qf[kk], s[km], 0, 0, 0);
        }

        // ---- mask + online softmax (per q row = l16; reduce over quads)
        float mx = -1e30f;
#pragma unroll
        for (int km = 0; km < 4; ++km)
#pragma unroll
            for (int r = 0; r < 4; ++r) {
                const int kl  = kb * 64 + km * 16 + quad * 4 + r;
                const int dlt = kl - l16;
                const bool ok = (dlt >= 1) && (dlt <= 128) && (kl >= kclip);
                const float sv = ok ? s[km][r] : -1e30f;
                s[km][r] = sv;
                mx = fmaxf(mx, sv);
            }
        mx = fmaxf(mx, __shfl_xor(mx, 16));
        mx = fmaxf(mx, __shfl_xor(mx, 32));
        const float mnew = fmaxf(fmaxf(m_run, mx), -1e20f);
        const float corr = expf(m_run - mnew);
        m_run = mnew;
        float rowsum = 0.f;
        unsigned cu[4][2];
#pragma unroll
        for (int km = 0; km < 4; ++km) {
#pragma unroll
            for (int r = 0; r < 4; ++r) {
                const float p = expf(s[km][r] - mnew);   // masked -> 0
                s[km][r] = p;
                rowsum += p;
            }
            cu[km][0] = pk2(s[km][0], s[km][1]);
            cu[km][1] = pk2(s[km][2], s[km][3]);
        }
        rowsum += __shfl_xor(rowsum, 16);
        rowsum += __shfl_xor(rowsum, 32);
        l_run = l_run * corr + rowsum;

        // ---- rescale O (row q=quad*4+r needs corr from a lane with that l16)
#pragma unroll
        for (int r = 0; r < 4; ++r) {
            const float f = __shfl(corr, (lane & 48) | (quad * 4 + r));
            oacc[0][r] *= f; oacc[1][r] *= f;
            oacc[2][r] *= f; oacc[3][r] *= f;
        }

        // ---- PV: O += P @ V  (A-frag via cross-quad shfl of cu packs)
#pragma unroll
        for (int kk = 0; kk < 2; ++kk) {
            bf16x8 vf[4];
#pragma unroll
            for (int dn = 0; dn < 4; ++dn) {
                int t = wb + kb * 64 + kk * 32 + quad * 8;
                t = (t >= 0 && t <= 2040) ? t : 0;       // p=0 for those slots
                vf[dn] = *(const bf16x8*)(Vb + (size_t)(dn * 16 + l16) * 2048 + t);
            }
            const int srcA = ((quad & 1) * 32) + l16;
            const int hi   = quad >> 1;
            const unsigned a0 = (unsigned)__shfl((int)cu[2*kk  ][0], srcA);
            const unsigned a1 = (unsigned)__shfl((int)cu[2*kk  ][1], srcA);
            const unsigned b0 = (unsigned)__shfl((int)cu[2*kk+1][0], srcA);
            const unsigned b1 = (unsigned)__shfl((int)cu[2*kk+1][1], srcA);
            const unsigned c0 = (unsigned)__shfl((int)cu[2*kk  ][0], srcA + 16);
            const unsigned c1 = (unsigned)__shfl((int)cu[2*kk  ][1], srcA + 16);
            const unsigned d0 = (unsigned)__shfl((int)cu[2*kk+1][0], srcA + 16);
            const unsigned d1 = (unsigned)__shfl((int)cu[2*kk+1][1], srcA + 16);
            union { unsigned u[4]; bf16x8 v; } af;
            af.u[0] = hi ? b0 : a0;
            af.u[1] = hi ? b1 : a1;
            af.u[2] = hi ? d0 : c0;
            af.u[3] = hi ? d1 : c1;
#pragma unroll
            for (int dn = 0; dn < 4; ++dn)
                oacc[dn] = __builtin_amdgcn_mfma_f32_16x16x32_bf16(
                    af.v, vf[dn], oacc[dn], 0, 0, 0);
        }
    }

    // ---- normalize + store bf16
    const float rl = 1.f / l_run;
#pragma unroll
    for (int r = 0; r < 4; ++r) {
        const float f = __shfl(rl, (lane & 48) | (quad * 4 + r));
        const int q = q0 + quad * 4 + r;
        __bf16* op = obf + ((size_t)(b * 2048 + q)) * 1024 + h * 64 + l16;
#pragma unroll
        for (int dn = 0; dn < 4; ++dn)
            op[dn * 16] = (__bf16)(oacc[dn][r] * f);
    }
}

// ------------------------------------------------------------------ p0 ----
// QKV GEMM + fused RoPE -> q_bf (scaled 0.125) / k_bf / vt_bf (transposed).
// 64x128 tile, grid 64*12=768 (3 blocks/CU), 4 waves 2x2.
__global__ __launch_bounds__(256, 4) void MultiAttention_60722247631706_p0(
    float* ws)
{
    __bf16* qbf    = (__bf16*)ws;
    __bf16* kbf    = (__bf16*)(ws + 2097152);
    __bf16* vtbf   = (__bf16*)(ws + 2621440);
    __bf16* xbf    = (__bf16*)(ws + 6291456);
    __bf16* wqkvbf = (__bf16*)(ws + 8388608);

    const int tid = threadIdx.x;

    __bf16* As = (__bf16*)smem;       // [64][64]
    __bf16* Bs = As + 64 * 64;        // [128][64]

    const int bid  = xcd_swz(blockIdx.x, 768);
    const int tm   = bid / 12;        // 0..63
    const int tn   = bid % 12;        // 0..11
    const int w    = tid >> 6;
    const int lane = tid & 63;
    const int wr   = w >> 1;
    const int wc   = w & 1;
    const int l16  = lane & 15;
    const int quad = lane >> 4;
    const int srow = lane >> 3;
    const int sch  = ((lane & 7) ^ srow) * 8;

    const __bf16* ga0 = xbf    + (size_t)(tm * 64  + w * 16 + srow) * 1024 + sch;
    const __bf16* gb0 = wqkvbf + (size_t)(tn * 128 + w * 32 + srow) * 1024 + sch;

    f32x4 zero = {0.f, 0.f, 0.f, 0.f};
    f32x4 acc[2][4];
#pragma unroll
    for (int mi = 0; mi < 2; ++mi)
#pragma unroll
        for (int ni = 0; ni < 4; ++ni) acc[mi][ni] = zero;

    for (int k0 = 0; k0 < 1024; k0 += 64) {
#pragma unroll
        for (int i = 0; i < 2; ++i)
            GLOAD_LDS16(ga0 + (size_t)i * 8 * 1024 + k0, As + (w * 16 + i * 8) * 64);
#pragma unroll
        for (int i = 0; i < 4; ++i)
            GLOAD_LDS16(gb0 + (size_t)i * 8 * 1024 + k0, Bs + (w * 32 + i * 8) * 64);
        __syncthreads();
#pragma unroll
        for (int kk = 0; kk < 2; ++kk) {
            const int cs = ((kk * 4 + quad) ^ (l16 & 7)) * 8;
            bf16x8 af[2], bfr[4];
#pragma unroll
            for (int mi = 0; mi < 2; ++mi)
                af[mi] = *(const bf16x8*)(As + (size_t)(wr * 32 + mi * 16 + l16) * 64 + cs);
#pragma unroll
            for (int ni = 0; ni < 4; ++ni)
                bfr[ni] = *(const bf16x8*)(Bs + (size_t)(wc * 64 + ni * 16 + l16) * 64 + cs);
#pragma unroll
            for (int mi = 0; mi < 2; ++mi)
#pragma unroll
                for (int ni = 0; ni < 4; ++ni)
                    acc[mi][ni] = __builtin_amdgcn_mfma_f32_16x16x32_bf16(
                        af[mi], bfr[ni], acc[mi][ni], 0, 0, 0);
        }
        __syncthreads();
    }

    const int mbase = tm * 64 + wr * 32;
    const int nbase = tn * 128 + wc * 64;   // multiple of 64 -> head-aligned

    if (nbase < 1280) {
        // Q (scaled) / K: RoPE pairs (ni 0,2)=(d,d+32), (ni 1,3)=(d+16,d+48)
        const bool isQ = nbase < 1024;
        const float inv1 = powf(10000.f, -(float)l16 / 32.f);
        const float inv2 = powf(10000.f, -(float)(16 + l16) / 32.f);
#pragma unroll
        for (int mi = 0; mi < 2; ++mi) {
#pragma unroll
            for (int r = 0; r < 4; ++r) {
                const int m = mbase + mi * 16 + quad * 4 + r;
                const int t = m & 2047;
                float v0 = acc[mi][0][r], v1 = acc[mi][1][r];
                float v2 = acc[mi][2][r], v3 = acc[mi][3][r];
                const float a1 = (float)t * inv1, a2 = (float)t * inv2;
                const float c1 = cosf(a1), s1 = sinf(a1);
                const float c2 = cosf(a2), s2 = sinf(a2);
                float n0 = v0 * c1 - v2 * s1;
                float n2 = v0 * s1 + v2 * c1;
                float n1 = v1 * c2 - v3 * s2;
                float n3 = v1 * s2 + v3 * c2;
                if (isQ) { n0 *= 0.125f; n1 *= 0.125f; n2 *= 0.125f; n3 *= 0.125f; }
                __bf16* dst = isQ
                    ? qbf + (size_t)m * 1024 + nbase + l16
                    : kbf + (size_t)m * 256 + (nbase - 1024) + l16;
                dst[0]  = (__bf16)n0; dst[16] = (__bf16)n1;
                dst[32] = (__bf16)n2; dst[48] = (__bf16)n3;
            }
        }
    } else {
        // V -> vt_bf transposed [b][kvh][d][t]; f32x4 over r = 4 consecutive t
        const int kvh = (nbase - 1280) >> 6;
        const int bb  = mbase >> 11;          // whole tile in one batch
        const int tb  = mbase & 2047;
#pragma unroll
        for (int mi = 0; mi < 2; ++mi) {
#pragma unroll
            for (int ni = 0; ni < 4; ++ni) {
                const int d = ni * 16 + l16;
                bf16x4 pv;
                pv[0] = (__bf16)acc[mi][ni][0]; pv[1] = (__bf16)acc[mi][ni][1];
                pv[2] = (__bf16)acc[mi][ni][2]; pv[3] = (__bf16)acc[mi][ni][3];
                *(bf16x4*)(vtbf + ((size_t)(bb * 4 + kvh) * 64 + d) * 2048
                           + tb + mi * 16 + quad * 4) = pv;
            }
        }
    }
}

// ---------------------------------------------------------------- ffn1 ----
// H = silu(o@W1^T): 128x128 tile, 4 waves, grid 32*32=1024 (4 blocks/CU).
__global__ __launch_bounds__(256, 4) void MultiAttention_60722247631706_ffn1(
    float* ws)
{
    __bf16* obf  = (__bf16*)(ws + 8388608);
    __bf16* w1bf = (__bf16*)(ws + 10485760);
    __bf16* hbf  = (__bf16*)ws;

    const int tid = threadIdx.x;

    __bf16* As = (__bf16*)smem;       // [128][64]
    __bf16* Bs = As + 128 * 64;       // [128][64]

    const int bid  = xcd_swz(blockIdx.x, 1024);
    const int tm   = bid >> 5;        // 0..31
    const int tn   = bid & 31;        // 0..31
    const int w    = tid >> 6;
    const int lane = tid & 63;
    const int wr   = w >> 1;
    const int wc   = w & 1;
    const int l16  = lane & 15;
    const int quad = lane >> 4;
    const int srow = lane >> 3;
    const int sch  = ((lane & 7) ^ srow) * 8;

    const __bf16* ga0 = obf  + (size_t)(tm * 128 + w * 32 + srow) * 1024 + sch;
    const __bf16* gb0 = w1bf + (size_t)(tn * 128 + w * 32 + srow) * 1024 + sch;

    f32x4 zero = {0.f, 0.f, 0.f, 0.f};
    f32x4 acc[4][4];
#pragma unroll
    for (int mi = 0; mi < 4; ++mi)
#pragma unroll
        for (int ni = 0; ni < 4; ++ni) acc[mi][ni] = zero;

    for (int k0 = 0; k0 < 1024; k0 += 64) {
#pragma unroll
        for (int i = 0; i < 4; ++i) {
            GLOAD_LDS16(ga0 + (size_t)i * 8 * 1024 + k0, As + (w * 32 + i * 8) * 64);
            GLOAD_LDS16(gb0 + (size_t)i * 8 * 1024 + k0, Bs + (w * 32 + i * 8) * 64);
        }
        __syncthreads();
#pragma unroll
        for (int kk = 0; kk < 2; ++kk) {
            const int cs = ((kk * 4 + quad) ^ (l16 & 7)) * 8;
            bf16x8 af[4], bfr[4];
#pragma unroll
            for (int mi = 0; mi < 4; ++mi)
                af[mi] = *(const bf16x8*)(As + (size_t)(wr * 64 + mi * 16 + l16) * 64 + cs);
#pragma unroll
            for (int ni = 0; ni < 4; ++ni)
                bfr[ni] = *(const bf16x8*)(Bs + (size_t)(wc * 64 + ni * 16 + l16) * 64 + cs);
#pragma unroll
            for (int mi = 0; mi < 4; ++mi)
#pragma unroll
                for (int ni = 0; ni < 4; ++ni)
                    acc[mi][ni] = __builtin_amdgcn_mfma_f32_16x16x32_bf16(
                        af[mi], bfr[ni], acc[mi][ni], 0, 0, 0);
        }
        __syncthreads();
    }

#pragma unroll
    for (int mi = 0; mi < 4; ++mi) {
#pragma unroll
        for (int r = 0; r < 4; ++r) {
            const int m = tm * 128 + wr * 64 + mi * 16 + quad * 4 + r;
            __bf16* hp = hbf + (size_t)m * 4096 + tn * 128 + wc * 64 + l16;
#pragma unroll
            for (int ni = 0; ni < 4; ++ni) {
                const float v = acc[mi][ni][r];
                hp[ni * 16] = (__bf16)(v / (1.f + expf(-v)));   // silu
            }
        }
    }
}

// ---------------------------------------------------------------- ffn2 ----
// out += H_ks @ W2_ks^T: 64x128 tile, split-K x2, grid 1024 (4/CU), atomicAdd.
__global__ __launch_bounds__(256, 4) void MultiAttention_60722247631706_ffn2(
    float* out, float* ws)
{
    __bf16* hbf  = (__bf16*)ws;
    __bf16* w2bf = (__bf16*)(ws + 8388608);

    int bid = xcd_swz(blockIdx.x, 1024);
    const int ks = bid >> 9;  bid &= 511;
    const int tm = bid >> 3;          // 0..63
    const int tn = bid & 7;           // 0..7
    const int kbase = ks * 2048;

    const int tid  = threadIdx.x;
    const int w    = tid >> 6;
    const int lane = tid & 63;
    const int wr   = w >> 1;          // 0..1 (M half, 32 rows)
    const int wc   = w & 1;           // 0..1 (N half, 64 cols)
    const int l16  = lane & 15;
    const int quad = lane >> 4;
    const int srow = lane >> 3;
    const int sch  = ((lane & 7) ^ srow) * 8;

    __bf16* As = (__bf16*)smem;       // [64][64]
    __bf16* Bs = As + 64 * 64;        // [128][64]

    const __bf16* ga0 = hbf  + (size_t)(tm * 64  + w * 16 + srow) * 4096 + kbase + sch;
    const __bf16* gb0 = w2bf + (size_t)(tn * 128 + w * 32 + srow) * 4096 + kbase + sch;

    f32x4 zero = {0.f, 0.f, 0.f, 0.f};
    f32x4 acc[2][4];
#pragma unroll
    for (int mi = 0; mi < 2; ++mi)
#pragma unroll
        for (int ni = 0; ni < 4; ++ni) acc[mi][ni] = zero;

    for (int k0 = 0; k0 < 2048; k0 += 64) {
#pragma unroll
        for (int i = 0; i < 2; ++i)
            GLOAD_LDS16(ga0 + (size_t)i * 8 * 4096 + k0, As + (w * 16 + i * 8) * 64);
#pragma unroll
        for (int i = 0; i < 4; ++i)
            GLOAD_LDS16(gb0 + (size_t)i * 8 * 4096 + k0, Bs + (w * 32 + i * 8) * 64);
        __syncthreads();
#pragma unroll
        for (int kk = 0; kk < 2; ++kk) {
            const int cs = ((kk * 4 + quad) ^ (l16 & 7)) * 8;
            bf16x8 af[2], bfr[4];
#pragma unroll
            for (int mi = 0; mi < 2; ++mi)
                af[mi] = *(const bf16x8*)(As + (size_t)(wr * 32 + mi * 16 + l16) * 64 + cs);
#pragma unroll
            for (int ni = 0; ni < 4; ++ni)
                bfr[ni] = *(const bf16x8*)(Bs + (size_t)(wc * 64 + ni * 16 + l16) * 64 + cs);
#pragma unroll
            for (int mi = 0; mi < 2; ++mi)
#pragma unroll
                for (int ni = 0; ni < 4; ++ni)
                    acc[mi][ni] = __builtin_amdgcn_mfma_f32_16x16x32_bf16(
                        af[mi], bfr[ni], acc[mi][ni], 0, 0, 0);
        }
        __syncthreads();
    }

#pragma unroll
    for (int mi = 0; mi < 2; ++mi) {
#pragma unroll
        for (int r = 0; r < 4; ++r) {
            const int m = tm * 64 + wr * 32 + mi * 16 + quad * 4 + r;
            float* op = out + (size_t)m * 1024 + tn * 128 + wc * 64 + l16;
#pragma unroll
            for (int ni = 0; ni < 4; ++ni)
                atomicAdd(op + ni * 16, acc[mi][ni][r]);
        }
    }
}

extern "C" void kernel_launch(void* const* d_in, const int* in_sizes, int n_in,
                              void* d_out, int out_size, void* d_ws, size_t ws_size,
                              hipStream_t stream)
{
    const float* x  = (const float*)d_in[0];
    const float* Wq = (const float*)d_in[1];
    const float* Wk = (const float*)d_in[2];
    const float* Wv = (const float*)d_in[3];
    const float* W1 = (const float*)d_in[4];
    const float* W2 = (const float*)d_in[5];
    float* out = (float*)d_out;
    float* ws  = (float*)d_ws;

    const int P0_LDS   = (64 + 128) * 64 * 2;              // 24576 B
    const int FFN1_LDS = 2 * 128 * 64 * 2;                 // 32768 B
    const int FFN2_LDS = (64 + 128) * 64 * 2;              // 24576 B

    // conv: x, Wq|Wk|Wv, W1 -> bf16
    MultiAttention_60722247631706_conv<<<2048, 256, 0, stream>>>(
        x, Wq, Wk, Wv, W1, W2, out, ws, 5);
    // p0: QKV GEMM + fused RoPE -> q_bf / k_bf / vt_bf
    MultiAttention_60722247631706_p0<<<768, 256, P0_LDS, stream>>>(ws);
    // attention v2 (no LDS) -> o_bf
    MultiAttention_60722247631706_attn<<<1024, 256, 0, stream>>>(ws);
    // FFN1 -> h_bf
    MultiAttention_60722247631706_ffn1<<<1024, 256, FFN1_LDS, stream>>>(ws);
    // conv: W2 -> bf16 (over dead o_bf) + zero `out`
    MultiAttention_60722247631706_conv<<<1024, 256, 0, stream>>>(
        x, Wq, Wk, Wv, W1, W2, out, ws, 6);
    // FFN2: split-K x2, atomicAdd into out
    MultiAttention_60722247631706_ffn2<<<1024, 256, FFN2_LDS, stream>>>(out, ws);
}